// Round 8
// baseline (581.112 us; speedup 1.0000x reference)
//
#include <hip/hip_runtime.h>
#include <math.h>

#define T_ 1024
#define D_ 3
#define H_ 64

typedef _Float16 f16x8 __attribute__((ext_vector_type(8)));
typedef _Float16 f16x4 __attribute__((ext_vector_type(4)));
typedef float f32x4 __attribute__((ext_vector_type(4)));

__device__ __forceinline__ float sigmoid_f(float x) {
    return __builtin_amdgcn_rcpf(1.0f + __expf(-x));
}

#define MFMA(A, B, C) __builtin_amdgcn_mfma_f32_16x16x32_f16((A), (B), (C), 0, 0, 0)

// Round-9 (3rd submit; two infra failures, kernel unchanged): R5 winner
// (transposed MFMA, 1x ds_write_b64 publish) + ONE change: isolated
// s_setprio(1) over the post-barrier ds_read + h-MFMA cluster. The two
// co-resident blocks per CU have independent barriers (phase-diverse); prio
// makes the MFMA-phase block win issue arbitration over the gate-phase block,
// whose 4 independent gate rows are latency-tolerant. Symmetric placement
// alternates priority with phase -> stabilizes anti-phase. Neutral if lockstep.
__global__ __launch_bounds__(256, 2) void gru_mfma11(
    const float* __restrict__ x1, const float* __restrict__ x2,
    const float* __restrict__ W_ih, const float* __restrict__ W_hh,
    const float* __restrict__ b_ih, const float* __restrict__ b_hh,
    const float* __restrict__ W1, const float* __restrict__ b1,
    const float* __restrict__ W2, const float* __restrict__ b2,
    float* __restrict__ out)
{
    const int lane = threadIdx.x & 63;
    const int w    = threadIdx.x >> 6;   // wave 0..3: owns units 16w..16w+15
    const int c    = lane & 15;          // A row (unit_out) / B-D col (seq)
    const int q    = lane >> 4;          // quad
    const int u    = 16 * w + c;         // A-side unit_out for W fragments
    const int u2   = 16 * w + 4 * q;     // D-side unit_out base (rows 4q+r)
    const int seq0 = blockIdx.x * 8;

    const float SRZ = -1.44269504f;      // -log2(e): r,z rows (exp2(-x) form)
    const float SN  =  2.88539008f;      // 2*log2(e): n rows (exp2(2x) form)
    const float gsc[3] = {SRZ, SRZ, SN};

    // ---- W_hh A-fragments (scaled): wf[g][ks][j] = s_g*W_hh[g*64+u][32ks+8q+j]
    f16x8 wf[3][2];
    #pragma unroll
    for (int g = 0; g < 3; ++g)
        #pragma unroll
        for (int ks = 0; ks < 2; ++ks) {
            const float* p = W_hh + (size_t)(g * 64 + u) * H_ + 32 * ks + q * 8;
            f16x8 v;
            #pragma unroll
            for (int j = 0; j < 8; ++j) v[j] = (_Float16)(p[j] * gsc[g]);
            wf[g][ks] = v;
        }

    // ---- W_ih A-fragments (scaled; nonzero only in q==0 lanes, j<3) ----
    f16x8 axf[3];
    #pragma unroll
    for (int g = 0; g < 3; ++g) {
        f16x8 v = {};
        if (q == 0) {
            #pragma unroll
            for (int d = 0; d < 3; ++d)
                v[d] = (_Float16)(W_ih[(size_t)(g * 64 + u) * D_ + d] * gsc[g]);
        }
        axf[g] = v;
    }

    // ---- bias C vectors (scaled), per D-row r: unit u2+r ----
    f32x4 Cr, Cz, Cxn, Chn;
    #pragma unroll
    for (int r = 0; r < 4; ++r) {
        Cr[r]  = (b_ih[u2 + r]       + b_hh[u2 + r])       * SRZ;
        Cz[r]  = (b_ih[64 + u2 + r]  + b_hh[64 + u2 + r])  * SRZ;
        Cxn[r] = b_ih[128 + u2 + r] * SN;
        Chn[r] = b_hh[128 + u2 + r] * SN;
    }

    // ---- x pointer for B-frag col c (seqs 0..7 = chain1, 8..15 = chain2) ----
    const float* xptr = (c < 8) ? (x1 + (size_t)(seq0 + c) * (T_ * D_))
                                : (x2 + (size_t)(seq0 + c - 8) * (T_ * D_));

    // h-tile double buffer: [seq][unit], stride 72 halves
    __shared__ alignas(16) _Float16 hb[2][16 * 72];
    __shared__ float dlds[8][68];

    float h[4];                          // units u2+0..3, seq c
    #pragma unroll
    for (int r = 0; r < 4; ++r) h[r] = 0.f;

    auto step = [&](int buf, float x0, float x1v, float x2v) {
        // publish h(t): ONE contiguous b64 write (units u2..u2+3 of seq c)
        f16x4 hp;
        #pragma unroll
        for (int r = 0; r < 4; ++r) hp[r] = (_Float16)h[r];
        *(f16x4*)&hb[buf][c * 72 + u2] = hp;
        // x-part MFMAs: independent of h(t), fill the pre-barrier gap.
        f16x8 bx = {};
        bx[0] = (_Float16)x0; bx[1] = (_Float16)x1v; bx[2] = (_Float16)x2v;
        f32x4 ar  = MFMA(axf[0], bx, Cr);
        f32x4 az  = MFMA(axf[1], bx, Cz);
        f32x4 axn = MFMA(axf[2], bx, Cxn);
        __syncthreads();
        // prio 1: win issue arbitration vs the other block's gate phase
        __builtin_amdgcn_s_setprio(1);
        const f16x8 b0 = *(const f16x8*)&hb[buf][c * 72 + q * 8];        // units 0..31
        const f16x8 b1 = *(const f16x8*)&hb[buf][c * 72 + 32 + q * 8];   // units 32..63

        ar  = MFMA(wf[0][0], b0, ar);
        az  = MFMA(wf[1][0], b0, az);
        f32x4 ahn = MFMA(wf[2][0], b0, Chn);
        ar  = MFMA(wf[0][1], b1, ar);
        az  = MFMA(wf[1][1], b1, az);
        ahn = MFMA(wf[2][1], b1, ahn);
        __builtin_amdgcn_s_setprio(0);

        // gates: ar,az hold -log2e*preact; axn,ahn hold 2log2e*parts
        #pragma unroll
        for (int r = 0; r < 4; ++r) {
            const float eu = __builtin_amdgcn_exp2f(ar[r]);   // e^{-pre_r}
            const float ev = __builtin_amdgcn_exp2f(az[r]);   // e^{-pre_z}
            const float pu = 1.0f + eu, pv = 1.0f + ev;
            const float inv = __builtin_amdgcn_rcpf(pu * pv);
            const float rr = pv * inv;                        // sigmoid(pre_r)
            const float zz = pu * inv;                        // sigmoid(pre_z)
            const float tt = axn[r] + rr * ahn[r];            // 2log2e * pre_n
            const float e2 = __builtin_amdgcn_exp2f(tt);      // e^{2 pre_n}
            const float nn = 1.0f - 2.0f * __builtin_amdgcn_rcpf(e2 + 1.0f);
            h[r] = nn + zz * (h[r] - nn);
        }
    };

    // x batched: float4 x3 = 12 floats = 4 steps; prefetch distance 4 steps
    const float4* xp4 = (const float4*)xptr;
    float4 xc[3];
    #pragma unroll
    for (int i = 0; i < 3; ++i) xc[i] = xp4[i];

    for (int t = 0; t < T_; t += 4) {
        float4 xn[3];
        const int tb = (t + 4 < T_) ? (3 * (t + 4)) / 4 : (3 * t) / 4;
        #pragma unroll
        for (int i = 0; i < 3; ++i) xn[i] = xp4[tb + i];
        step(0, xc[0].x, xc[0].y, xc[0].z);
        step(1, xc[0].w, xc[1].x, xc[1].y);
        step(0, xc[1].z, xc[1].w, xc[2].x);
        step(1, xc[2].y, xc[2].z, xc[2].w);
        #pragma unroll
        for (int i = 0; i < 3; ++i) xc[i] = xn[i];
    }

    // ---- epilogue: |h1-h2| -> Linear(64,32)+ReLU -> Linear(32,1)+sigmoid ----
    // lane holds h_last[seq c][units u2+0..3]; pair seq c <-> c^8 is lane^8.
    {
        float d4[4];
        #pragma unroll
        for (int r = 0; r < 4; ++r) {
            const float o = __shfl_xor(h[r], 8);
            d4[r] = fabsf(h[r] - o);
        }
        if (c < 8) {
            float4 v = {d4[0], d4[1], d4[2], d4[3]};
            *(float4*)&dlds[c][u2] = v;          // units u2..u2+3, contiguous
        }
    }
    __syncthreads();
    if (w == 0) {
        const int s = lane >> 3;   // seq within block 0..7
        const int b = lane & 7;    // hidden-row group base
        float am[4];
        #pragma unroll
        for (int i = 0; i < 4; ++i) am[i] = b1[b + 8 * i];
        #pragma unroll
        for (int k4 = 0; k4 < 16; ++k4) {
            const float4 dvec = *(const float4*)&dlds[s][k4 * 4];
            #pragma unroll
            for (int i = 0; i < 4; ++i) {
                const float4 wv = *(const float4*)&W1[(b + 8 * i) * H_ + k4 * 4];
                am[i] += dvec.x * wv.x + dvec.y * wv.y + dvec.z * wv.z + dvec.w * wv.w;
            }
        }
        float part = 0.f;
        #pragma unroll
        for (int i = 0; i < 4; ++i) part += fmaxf(am[i], 0.f) * W2[b + 8 * i];
        part += __shfl_xor(part, 1);
        part += __shfl_xor(part, 2);
        part += __shfl_xor(part, 4);
        if (b == 0) out[seq0 + s] = sigmoid_f(part + b2[0]);
    }
}

extern "C" void kernel_launch(void* const* d_in, const int* in_sizes, int n_in,
                              void* d_out, int out_size, void* d_ws, size_t ws_size,
                              hipStream_t stream) {
    const float* x1   = (const float*)d_in[0];
    const float* x2   = (const float*)d_in[1];
    const float* W_ih = (const float*)d_in[2];
    const float* W_hh = (const float*)d_in[3];
    const float* b_ih = (const float*)d_in[4];
    const float* b_hh = (const float*)d_in[5];
    const float* W1   = (const float*)d_in[6];
    const float* b1   = (const float*)d_in[7];
    const float* W2   = (const float*)d_in[8];
    const float* b2   = (const float*)d_in[9];

    const int B = in_sizes[0] / (T_ * D_);      // 4096
    dim3 grid(B / 8), block(256);
    gru_mfma11<<<grid, block, 0, stream>>>(x1, x2, W_ih, W_hh, b_ih, b_hh,
                                           W1, b1, W2, b2, (float*)d_out);
}

// Round 9
// 550.746 us; speedup vs baseline: 1.0551x; 1.0551x over previous
//
#include <hip/hip_runtime.h>
#include <math.h>

#define T_ 1024
#define D_ 3
#define H_ 64

typedef _Float16 f16x8 __attribute__((ext_vector_type(8)));
typedef _Float16 f16x4 __attribute__((ext_vector_type(4)));
typedef float f32x4 __attribute__((ext_vector_type(4)));

__device__ __forceinline__ float sigmoid_f(float x) {
    return __builtin_amdgcn_rcpf(1.0f + __expf(-x));
}

#define MFMA(A, B, C) __builtin_amdgcn_mfma_f32_16x16x32_f16((A), (B), (C), 0, 0, 0)

// Round-10: exact revert to the R5 winner (531 us). Transposed MFMA
// (preact^T[unit,seq] = MFMA(A=W_frag, B=h_frag^T)) so the h publish is a
// single contiguous ds_write_b64; pre-barrier x-MFMAs; 4-step unroll with
// 4-step x prefetch; __syncthreads per step. s_setprio REMOVED (R8 A/B:
// isolated setprio = 549 us, -3% — priority flipping perturbs the natural
// issue fairness between the two co-resident blocks).
__global__ __launch_bounds__(256, 2) void gru_mfma12(
    const float* __restrict__ x1, const float* __restrict__ x2,
    const float* __restrict__ W_ih, const float* __restrict__ W_hh,
    const float* __restrict__ b_ih, const float* __restrict__ b_hh,
    const float* __restrict__ W1, const float* __restrict__ b1,
    const float* __restrict__ W2, const float* __restrict__ b2,
    float* __restrict__ out)
{
    const int lane = threadIdx.x & 63;
    const int w    = threadIdx.x >> 6;   // wave 0..3: owns units 16w..16w+15
    const int c    = lane & 15;          // A row (unit_out) / B-D col (seq)
    const int q    = lane >> 4;          // quad
    const int u    = 16 * w + c;         // A-side unit_out for W fragments
    const int u2   = 16 * w + 4 * q;     // D-side unit_out base (rows 4q+r)
    const int seq0 = blockIdx.x * 8;

    const float SRZ = -1.44269504f;      // -log2(e): r,z rows (exp2(-x) form)
    const float SN  =  2.88539008f;      // 2*log2(e): n rows (exp2(2x) form)
    const float gsc[3] = {SRZ, SRZ, SN};

    // ---- W_hh A-fragments (scaled): wf[g][ks][j] = s_g*W_hh[g*64+u][32ks+8q+j]
    f16x8 wf[3][2];
    #pragma unroll
    for (int g = 0; g < 3; ++g)
        #pragma unroll
        for (int ks = 0; ks < 2; ++ks) {
            const float* p = W_hh + (size_t)(g * 64 + u) * H_ + 32 * ks + q * 8;
            f16x8 v;
            #pragma unroll
            for (int j = 0; j < 8; ++j) v[j] = (_Float16)(p[j] * gsc[g]);
            wf[g][ks] = v;
        }

    // ---- W_ih A-fragments (scaled; nonzero only in q==0 lanes, j<3) ----
    f16x8 axf[3];
    #pragma unroll
    for (int g = 0; g < 3; ++g) {
        f16x8 v = {};
        if (q == 0) {
            #pragma unroll
            for (int d = 0; d < 3; ++d)
                v[d] = (_Float16)(W_ih[(size_t)(g * 64 + u) * D_ + d] * gsc[g]);
        }
        axf[g] = v;
    }

    // ---- bias C vectors (scaled), per D-row r: unit u2+r ----
    f32x4 Cr, Cz, Cxn, Chn;
    #pragma unroll
    for (int r = 0; r < 4; ++r) {
        Cr[r]  = (b_ih[u2 + r]       + b_hh[u2 + r])       * SRZ;
        Cz[r]  = (b_ih[64 + u2 + r]  + b_hh[64 + u2 + r])  * SRZ;
        Cxn[r] = b_ih[128 + u2 + r] * SN;
        Chn[r] = b_hh[128 + u2 + r] * SN;
    }

    // ---- x pointer for B-frag col c (seqs 0..7 = chain1, 8..15 = chain2) ----
    const float* xptr = (c < 8) ? (x1 + (size_t)(seq0 + c) * (T_ * D_))
                                : (x2 + (size_t)(seq0 + c - 8) * (T_ * D_));

    // h-tile double buffer: [seq][unit], stride 72 halves
    __shared__ alignas(16) _Float16 hb[2][16 * 72];
    __shared__ float dlds[8][68];

    float h[4];                          // units u2+0..3, seq c
    #pragma unroll
    for (int r = 0; r < 4; ++r) h[r] = 0.f;

    auto step = [&](int buf, float x0, float x1v, float x2v) {
        // publish h(t): ONE contiguous b64 write (units u2..u2+3 of seq c)
        f16x4 hp;
        #pragma unroll
        for (int r = 0; r < 4; ++r) hp[r] = (_Float16)h[r];
        *(f16x4*)&hb[buf][c * 72 + u2] = hp;
        // x-part MFMAs: independent of h(t), fill the pre-barrier gap.
        f16x8 bx = {};
        bx[0] = (_Float16)x0; bx[1] = (_Float16)x1v; bx[2] = (_Float16)x2v;
        f32x4 ar  = MFMA(axf[0], bx, Cr);
        f32x4 az  = MFMA(axf[1], bx, Cz);
        f32x4 axn = MFMA(axf[2], bx, Cxn);
        __syncthreads();
        const f16x8 b0 = *(const f16x8*)&hb[buf][c * 72 + q * 8];        // units 0..31
        const f16x8 b1 = *(const f16x8*)&hb[buf][c * 72 + 32 + q * 8];   // units 32..63

        ar  = MFMA(wf[0][0], b0, ar);
        az  = MFMA(wf[1][0], b0, az);
        f32x4 ahn = MFMA(wf[2][0], b0, Chn);
        ar  = MFMA(wf[0][1], b1, ar);
        az  = MFMA(wf[1][1], b1, az);
        ahn = MFMA(wf[2][1], b1, ahn);

        // gates: ar,az hold -log2e*preact; axn,ahn hold 2log2e*parts
        #pragma unroll
        for (int r = 0; r < 4; ++r) {
            const float eu = __builtin_amdgcn_exp2f(ar[r]);   // e^{-pre_r}
            const float ev = __builtin_amdgcn_exp2f(az[r]);   // e^{-pre_z}
            const float pu = 1.0f + eu, pv = 1.0f + ev;
            const float inv = __builtin_amdgcn_rcpf(pu * pv);
            const float rr = pv * inv;                        // sigmoid(pre_r)
            const float zz = pu * inv;                        // sigmoid(pre_z)
            const float tt = axn[r] + rr * ahn[r];            // 2log2e * pre_n
            const float e2 = __builtin_amdgcn_exp2f(tt);      // e^{2 pre_n}
            const float nn = 1.0f - 2.0f * __builtin_amdgcn_rcpf(e2 + 1.0f);
            h[r] = nn + zz * (h[r] - nn);
        }
    };

    // x batched: float4 x3 = 12 floats = 4 steps; prefetch distance 4 steps
    const float4* xp4 = (const float4*)xptr;
    float4 xc[3];
    #pragma unroll
    for (int i = 0; i < 3; ++i) xc[i] = xp4[i];

    for (int t = 0; t < T_; t += 4) {
        float4 xn[3];
        const int tb = (t + 4 < T_) ? (3 * (t + 4)) / 4 : (3 * t) / 4;
        #pragma unroll
        for (int i = 0; i < 3; ++i) xn[i] = xp4[tb + i];
        step(0, xc[0].x, xc[0].y, xc[0].z);
        step(1, xc[0].w, xc[1].x, xc[1].y);
        step(0, xc[1].z, xc[1].w, xc[2].x);
        step(1, xc[2].y, xc[2].z, xc[2].w);
        #pragma unroll
        for (int i = 0; i < 3; ++i) xc[i] = xn[i];
    }

    // ---- epilogue: |h1-h2| -> Linear(64,32)+ReLU -> Linear(32,1)+sigmoid ----
    // lane holds h_last[seq c][units u2+0..3]; pair seq c <-> c^8 is lane^8.
    {
        float d4[4];
        #pragma unroll
        for (int r = 0; r < 4; ++r) {
            const float o = __shfl_xor(h[r], 8);
            d4[r] = fabsf(h[r] - o);
        }
        if (c < 8) {
            float4 v = {d4[0], d4[1], d4[2], d4[3]};
            *(float4*)&dlds[c][u2] = v;          // units u2..u2+3, contiguous
        }
    }
    __syncthreads();
    if (w == 0) {
        const int s = lane >> 3;   // seq within block 0..7
        const int b = lane & 7;    // hidden-row group base
        float am[4];
        #pragma unroll
        for (int i = 0; i < 4; ++i) am[i] = b1[b + 8 * i];
        #pragma unroll
        for (int k4 = 0; k4 < 16; ++k4) {
            const float4 dvec = *(const float4*)&dlds[s][k4 * 4];
            #pragma unroll
            for (int i = 0; i < 4; ++i) {
                const float4 wv = *(const float4*)&W1[(b + 8 * i) * H_ + k4 * 4];
                am[i] += dvec.x * wv.x + dvec.y * wv.y + dvec.z * wv.z + dvec.w * wv.w;
            }
        }
        float part = 0.f;
        #pragma unroll
        for (int i = 0; i < 4; ++i) part += fmaxf(am[i], 0.f) * W2[b + 8 * i];
        part += __shfl_xor(part, 1);
        part += __shfl_xor(part, 2);
        part += __shfl_xor(part, 4);
        if (b == 0) out[seq0 + s] = sigmoid_f(part + b2[0]);
    }
}

extern "C" void kernel_launch(void* const* d_in, const int* in_sizes, int n_in,
                              void* d_out, int out_size, void* d_ws, size_t ws_size,
                              hipStream_t stream) {
    const float* x1   = (const float*)d_in[0];
    const float* x2   = (const float*)d_in[1];
    const float* W_ih = (const float*)d_in[2];
    const float* W_hh = (const float*)d_in[3];
    const float* b_ih = (const float*)d_in[4];
    const float* b_hh = (const float*)d_in[5];
    const float* W1   = (const float*)d_in[6];
    const float* b1   = (const float*)d_in[7];
    const float* W2   = (const float*)d_in[8];
    const float* b2   = (const float*)d_in[9];

    const int B = in_sizes[0] / (T_ * D_);      // 4096
    dim3 grid(B / 8), block(256);
    gru_mfma12<<<grid, block, 0, stream>>>(x1, x2, W_ih, W_hh, b_ih, b_hh,
                                           W1, b1, W2, b2, (float*)d_out);
}